// Round 1
// baseline (738.330 us; speedup 1.0000x reference)
//
#include <hip/hip_runtime.h>
#include <math.h>

#define N_TOK   16384
#define EDIM    64
#define NE      4096
#define NSLICE  8
#define CSLICE  (NE / NSLICE)            /* 512 codes per slice   */
#define CHUNK   128                      /* codes per LDS chunk   */
#define ZQ_OFF  1
#define IDX_OFF (1 + N_TOK * EDIM)       /* 1048577 */
#define PERP_OFF (IDX_OFF + N_TOK)       /* 1064961 */

typedef unsigned long long u64;

// ---------------------------------------------------------------------------
// Kernel A: per-row squared norms replicating numpy pairwise_sum (n=64 path:
// 8 accumulators stride 8, then ((r0+r1)+(r2+r3))+((r4+r5)+(r6+r7))),
// with products ROUNDED before summation (contract off). Also zero-inits
// the histogram and loss accumulator in ws.
// ---------------------------------------------------------------------------
__global__ __launch_bounds__(256) void norms_zero_kernel(
    const float* __restrict__ z, const float* __restrict__ cb,
    float* __restrict__ nz, float* __restrict__ ne,
    int* __restrict__ hist, float* __restrict__ lossAcc) {
#pragma clang fp contract(off)
    int i = blockIdx.x * 256 + threadIdx.x;
    if (i < NE) hist[i] = 0;
    if (i == 0) lossAcc[0] = 0.0f;
    const float* row;
    float* dst;
    if (i < N_TOK)            { row = z  + (size_t)i * EDIM;           dst = nz + i; }
    else if (i < N_TOK + NE)  { row = cb + (size_t)(i - N_TOK) * EDIM; dst = ne + (i - N_TOK); }
    else return;

    float r[8];
#pragma unroll
    for (int j = 0; j < 8; ++j) { float v = row[j]; r[j] = v * v; }
#pragma unroll
    for (int b = 8; b < 64; b += 8) {
#pragma unroll
        for (int j = 0; j < 8; ++j) { float v = row[b + j]; r[j] = r[j] + v * v; }
    }
    dst[0] = ((r[0] + r[1]) + (r[2] + r[3])) + ((r[4] + r[5]) + (r[6] + r[7]));
}

// ---------------------------------------------------------------------------
// Kernel B: distances + per-slice argmin.
// grid = (64 token-blocks, 8 code-slices), 256 thr. One thread = one token,
// z in 64 VGPRs. Codebook chunk (128 codes = 32 KB) staged in LDS; inner
// reads are wave-uniform (broadcast, conflict-free). Dot = sequential
// k-ascending FMA chain (matches BLAS sgemm accumulation). 4 codes in
// flight for ILP. d = (nz + ne[k]) - 2*dot  (2*dot exact -> contraction-safe).
// Argmin packed as (float_bits(d)<<32)|k : d>0 so bits are monotone; u64 min
// gives lowest-k tie-break, matching np.argmin first-occurrence.
// ---------------------------------------------------------------------------
__global__ __launch_bounds__(256) void dist_argmin_kernel(
    const float* __restrict__ z, const float* __restrict__ cb,
    const float* __restrict__ nz, const float* __restrict__ ne,
    u64* __restrict__ part) {
    __shared__ float se[CHUNK * EDIM];   // 32 KB
    __shared__ float sne[CHUNK];
    const int tid   = threadIdx.x;
    const int token = blockIdx.x * 256 + tid;
    const int slice = blockIdx.y;

    float zr[EDIM];
    {
        const float4* zp = (const float4*)(z + (size_t)token * EDIM);
#pragma unroll
        for (int j = 0; j < 16; ++j) {
            float4 v = zp[j];
            zr[4 * j + 0] = v.x; zr[4 * j + 1] = v.y;
            zr[4 * j + 2] = v.z; zr[4 * j + 3] = v.w;
        }
    }
    const float tnz = nz[token];
    u64 best = ~0ull;

#pragma unroll 1
    for (int c = 0; c < CSLICE / CHUNK; ++c) {
        const int kbase = slice * CSLICE + c * CHUNK;
        {
            const float4* src = (const float4*)(cb + (size_t)kbase * EDIM);
            float4* dst = (float4*)se;
#pragma unroll
            for (int r = 0; r < (CHUNK * EDIM / 4) / 256; ++r)
                dst[r * 256 + tid] = src[r * 256 + tid];
            if (tid < CHUNK / 4)
                ((float4*)sne)[tid] = ((const float4*)(ne + kbase))[tid];
        }
        __syncthreads();

#pragma unroll 1
        for (int k = 0; k < CHUNK; k += 4) {
            const float* e0 = se + (k + 0) * EDIM;
            const float* e1 = se + (k + 1) * EDIM;
            const float* e2 = se + (k + 2) * EDIM;
            const float* e3 = se + (k + 3) * EDIM;
            float d0 = 0.f, d1 = 0.f, d2 = 0.f, d3 = 0.f;
#pragma unroll
            for (int j = 0; j < EDIM; ++j) {
                d0 = __builtin_fmaf(zr[j], e0[j], d0);
                d1 = __builtin_fmaf(zr[j], e1[j], d1);
                d2 = __builtin_fmaf(zr[j], e2[j], d2);
                d3 = __builtin_fmaf(zr[j], e3[j], d3);
            }
            float t0 = (tnz + sne[k + 0]) - 2.0f * d0;
            float t1 = (tnz + sne[k + 1]) - 2.0f * d1;
            float t2 = (tnz + sne[k + 2]) - 2.0f * d2;
            float t3 = (tnz + sne[k + 3]) - 2.0f * d3;
            u64 p;
            p = ((u64)__float_as_uint(t0) << 32) | (u64)(kbase + k + 0); if (p < best) best = p;
            p = ((u64)__float_as_uint(t1) << 32) | (u64)(kbase + k + 1); if (p < best) best = p;
            p = ((u64)__float_as_uint(t2) << 32) | (u64)(kbase + k + 2); if (p < best) best = p;
            p = ((u64)__float_as_uint(t3) << 32) | (u64)(kbase + k + 3); if (p < best) best = p;
        }
        __syncthreads();
    }
    part[(size_t)slice * N_TOK + token] = best;
}

// ---------------------------------------------------------------------------
// Kernel C: combine 8 slice-partials (u64 min keeps first-index tie-break),
// write idx as float, histogram, gather z_q, write z_q_st = z + (z_q - z)
// exactly as the reference computes it, and accumulate sum((z_q - z)^2).
// ---------------------------------------------------------------------------
__global__ __launch_bounds__(256) void reduce_gather_kernel(
    const float* __restrict__ z, const float* __restrict__ cb,
    const u64* __restrict__ part, int* __restrict__ hist,
    float* __restrict__ lossAcc, float* __restrict__ out) {
    const int t = blockIdx.x * 256 + threadIdx.x;
    u64 best = part[t];
#pragma unroll
    for (int s = 1; s < NSLICE; ++s) {
        u64 p = part[(size_t)s * N_TOK + t];
        if (p < best) best = p;
    }
    const int idx = (int)(best & 0xFFFFFFFFull);
    out[IDX_OFF + t] = (float)idx;
    atomicAdd(&hist[idx], 1);

    const float4* ev = (const float4*)(cb + (size_t)idx * EDIM);
    const float4* zv = (const float4*)(z + (size_t)t * EDIM);
    float* o = out + ZQ_OFF + (size_t)t * EDIM;  // out+1: only 4B-aligned -> scalar stores
    float acc = 0.0f;
#pragma unroll
    for (int j = 0; j < 16; ++j) {
        float4 e = ev[j], zz = zv[j];
        float d;
        d = e.x - zz.x; o[4 * j + 0] = zz.x + d; acc = __builtin_fmaf(d, d, acc);
        d = e.y - zz.y; o[4 * j + 1] = zz.y + d; acc = __builtin_fmaf(d, d, acc);
        d = e.z - zz.z; o[4 * j + 2] = zz.z + d; acc = __builtin_fmaf(d, d, acc);
        d = e.w - zz.w; o[4 * j + 3] = zz.w + d; acc = __builtin_fmaf(d, d, acc);
    }
    __shared__ float red[256];
    red[threadIdx.x] = acc;
    __syncthreads();
    for (int s = 128; s > 0; s >>= 1) {
        if (threadIdx.x < s) red[threadIdx.x] += red[threadIdx.x + s];
        __syncthreads();
    }
    if (threadIdx.x == 0) atomicAdd(lossAcc, red[0]);
}

// ---------------------------------------------------------------------------
// Kernel D: perplexity from histogram + loss finalize.
// loss = m + 0.25*m with m = S/2^20 (exact power-of-two divides).
// ---------------------------------------------------------------------------
__global__ __launch_bounds__(256) void finalize_kernel(
    const int* __restrict__ hist, const float* __restrict__ lossAcc,
    float* __restrict__ out) {
    __shared__ float red[256];
    float acc = 0.0f;
    for (int i = threadIdx.x; i < NE; i += 256) {
        float e = (float)hist[i] * (1.0f / 16384.0f);  // exact /n_tokens
        acc += e * logf(e + 1e-10f);
    }
    red[threadIdx.x] = acc;
    __syncthreads();
    for (int s = 128; s > 0; s >>= 1) {
        if (threadIdx.x < s) red[threadIdx.x] += red[threadIdx.x + s];
        __syncthreads();
    }
    if (threadIdx.x == 0) {
        out[PERP_OFF] = expf(-red[0]);
        float m = lossAcc[0] * (1.0f / 1048576.0f);    // exact /B*T*E
        out[0] = m + 0.25f * m;
    }
}

extern "C" void kernel_launch(void* const* d_in, const int* in_sizes, int n_in,
                              void* d_out, int out_size, void* d_ws, size_t ws_size,
                              hipStream_t stream) {
    const float* z  = (const float*)d_in[0];
    const float* cb = (const float*)d_in[1];
    float* out = (float*)d_out;

    char* ws = (char*)d_ws;
    u64*   part    = (u64*)ws;                                  // 1 MB
    float* nz      = (float*)(ws + (size_t)NSLICE * N_TOK * 8); // 64 KB
    float* ne      = nz + N_TOK;                                // 16 KB
    int*   hist    = (int*)(ne + NE);                           // 16 KB
    float* lossAcc = (float*)(hist + NE);                       // 4 B

    hipLaunchKernelGGL(norms_zero_kernel, dim3(80), dim3(256), 0, stream,
                       z, cb, nz, ne, hist, lossAcc);
    hipLaunchKernelGGL(dist_argmin_kernel, dim3(64, NSLICE), dim3(256), 0, stream,
                       z, cb, nz, ne, part);
    hipLaunchKernelGGL(reduce_gather_kernel, dim3(64), dim3(256), 0, stream,
                       z, cb, part, hist, lossAcc, out);
    hipLaunchKernelGGL(finalize_kernel, dim3(1), dim3(256), 0, stream,
                       hist, lossAcc, out);
}

// Round 2
// 216.596 us; speedup vs baseline: 3.4088x; 3.4088x over previous
//
#include <hip/hip_runtime.h>
#include <math.h>

#define N_TOK   16384
#define EDIM    64
#define NE      4096
#define NSLICE  16
#define CSLICE  (NE / NSLICE)            /* 256 codes per slice   */
#define CHUNK   128                      /* codes per LDS chunk   */
#define ZQ_OFF  1
#define IDX_OFF (1 + N_TOK * EDIM)       /* 1048577 */
#define PERP_OFF (IDX_OFF + N_TOK)       /* 1064961 */

typedef unsigned long long u64;

// ---------------------------------------------------------------------------
// Kernel A: per-row squared norms replicating numpy pairwise_sum (n=64 path:
// 8 accumulators stride 8, then ((r0+r1)+(r2+r3))+((r4+r5)+(r6+r7))),
// with products ROUNDED before summation (contract off). Also zero-inits
// the histogram and loss accumulator in ws.
// ---------------------------------------------------------------------------
__global__ __launch_bounds__(256) void norms_zero_kernel(
    const float* __restrict__ z, const float* __restrict__ cb,
    float* __restrict__ nz, float* __restrict__ ne,
    int* __restrict__ hist, float* __restrict__ lossAcc) {
#pragma clang fp contract(off)
    int i = blockIdx.x * 256 + threadIdx.x;
    if (i < NE) hist[i] = 0;
    if (i == 0) lossAcc[0] = 0.0f;
    const float* row;
    float* dst;
    if (i < N_TOK)            { row = z  + (size_t)i * EDIM;           dst = nz + i; }
    else if (i < N_TOK + NE)  { row = cb + (size_t)(i - N_TOK) * EDIM; dst = ne + (i - N_TOK); }
    else return;

    float r[8];
#pragma unroll
    for (int j = 0; j < 8; ++j) { float v = row[j]; r[j] = v * v; }
#pragma unroll
    for (int b = 8; b < 64; b += 8) {
#pragma unroll
        for (int j = 0; j < 8; ++j) { float v = row[b + j]; r[j] = r[j] + v * v; }
    }
    dst[0] = ((r[0] + r[1]) + (r[2] + r[3])) + ((r[4] + r[5]) + (r[6] + r[7]));
}

// ---------------------------------------------------------------------------
// Kernel B: distances + per-slice argmin.
// One thread = one token, z resident in 64 VGPRs. Codebook chunk (128 codes,
// 32 KB) staged in LDS, read as wave-uniform broadcasts (conflict-free).
// 2 codes in flight per k-iter, e-values loaded float4-at-a-time and consumed
// immediately -> small live set. __launch_bounds__(256,3) caps VGPR at ~168
// so 3 blocks/CU stay resident (vs 256 VGPR / 1-2 blocks before).
// The per-(token,code) dot is the SAME sequential j-ascending FMA chain as
// the passing round-1 kernel (bitwise-identical d -> idx tie-breaks exact).
// d = fma(-2, dot, nz+ne[k]) == (nz+ne[k]) - 2*dot bitwise (2*dot exact).
// Argmin packed (d_bits<<32)|k: d>0 so monotone; u64 min = first-index tie.
// ---------------------------------------------------------------------------
__global__ __launch_bounds__(256, 3) void dist_argmin_kernel(
    const float* __restrict__ z, const float* __restrict__ cb,
    const float* __restrict__ nz, const float* __restrict__ ne,
    u64* __restrict__ part) {
    __shared__ float se[CHUNK * EDIM];   // 32 KB
    __shared__ float sne[CHUNK];
    const int tid   = threadIdx.x;
    const int token = blockIdx.x * 256 + tid;
    const int slice = blockIdx.y;

    float zr[EDIM];
    {
        const float4* zp = (const float4*)(z + (size_t)token * EDIM);
#pragma unroll
        for (int j = 0; j < 16; ++j) {
            float4 v = zp[j];
            zr[4 * j + 0] = v.x; zr[4 * j + 1] = v.y;
            zr[4 * j + 2] = v.z; zr[4 * j + 3] = v.w;
        }
    }
    const float tnz = nz[token];
    u64 best = ~0ull;

#pragma unroll 1
    for (int c = 0; c < CSLICE / CHUNK; ++c) {
        const int kbase = slice * CSLICE + c * CHUNK;
        {
            const float4* src = (const float4*)(cb + (size_t)kbase * EDIM);
            float4* dst = (float4*)se;
#pragma unroll
            for (int r = 0; r < (CHUNK * EDIM / 4) / 256; ++r)
                dst[r * 256 + tid] = src[r * 256 + tid];
            if (tid < CHUNK / 4)
                ((float4*)sne)[tid] = ((const float4*)(ne + kbase))[tid];
        }
        __syncthreads();

#pragma unroll 1
        for (int k = 0; k < CHUNK; k += 2) {
            const float4* e0 = (const float4*)(se + (size_t)(k + 0) * EDIM);
            const float4* e1 = (const float4*)(se + (size_t)(k + 1) * EDIM);
            float d0 = 0.f, d1 = 0.f;
#pragma unroll
            for (int q = 0; q < 16; ++q) {
                float4 a = e0[q];
                float4 b = e1[q];
                d0 = __builtin_fmaf(zr[4 * q + 0], a.x, d0);
                d0 = __builtin_fmaf(zr[4 * q + 1], a.y, d0);
                d0 = __builtin_fmaf(zr[4 * q + 2], a.z, d0);
                d0 = __builtin_fmaf(zr[4 * q + 3], a.w, d0);
                d1 = __builtin_fmaf(zr[4 * q + 0], b.x, d1);
                d1 = __builtin_fmaf(zr[4 * q + 1], b.y, d1);
                d1 = __builtin_fmaf(zr[4 * q + 2], b.z, d1);
                d1 = __builtin_fmaf(zr[4 * q + 3], b.w, d1);
            }
            float t0 = __builtin_fmaf(-2.0f, d0, tnz + sne[k + 0]);
            float t1 = __builtin_fmaf(-2.0f, d1, tnz + sne[k + 1]);
            u64 p;
            p = ((u64)__float_as_uint(t0) << 32) | (u64)(kbase + k + 0); if (p < best) best = p;
            p = ((u64)__float_as_uint(t1) << 32) | (u64)(kbase + k + 1); if (p < best) best = p;
        }
        __syncthreads();
    }
    part[(size_t)slice * N_TOK + token] = best;
}

// ---------------------------------------------------------------------------
// Kernel C: combine 16 slice-partials (u64 min keeps first-index tie-break),
// write idx as float, histogram, gather z_q, write z_q_st = z + (z_q - z)
// exactly as the reference computes it, and accumulate sum((z_q - z)^2).
// ---------------------------------------------------------------------------
__global__ __launch_bounds__(256) void reduce_gather_kernel(
    const float* __restrict__ z, const float* __restrict__ cb,
    const u64* __restrict__ part, int* __restrict__ hist,
    float* __restrict__ lossAcc, float* __restrict__ out) {
    const int t = blockIdx.x * 256 + threadIdx.x;
    u64 best = part[t];
#pragma unroll
    for (int s = 1; s < NSLICE; ++s) {
        u64 p = part[(size_t)s * N_TOK + t];
        if (p < best) best = p;
    }
    const int idx = (int)(best & 0xFFFFFFFFull);
    out[IDX_OFF + t] = (float)idx;
    atomicAdd(&hist[idx], 1);

    const float4* ev = (const float4*)(cb + (size_t)idx * EDIM);
    const float4* zv = (const float4*)(z + (size_t)t * EDIM);
    float* o = out + ZQ_OFF + (size_t)t * EDIM;  // out+1: only 4B-aligned -> scalar stores
    float acc = 0.0f;
#pragma unroll
    for (int j = 0; j < 16; ++j) {
        float4 e = ev[j], zz = zv[j];
        float d;
        d = e.x - zz.x; o[4 * j + 0] = zz.x + d; acc = __builtin_fmaf(d, d, acc);
        d = e.y - zz.y; o[4 * j + 1] = zz.y + d; acc = __builtin_fmaf(d, d, acc);
        d = e.z - zz.z; o[4 * j + 2] = zz.z + d; acc = __builtin_fmaf(d, d, acc);
        d = e.w - zz.w; o[4 * j + 3] = zz.w + d; acc = __builtin_fmaf(d, d, acc);
    }
    __shared__ float red[256];
    red[threadIdx.x] = acc;
    __syncthreads();
    for (int s = 128; s > 0; s >>= 1) {
        if (threadIdx.x < s) red[threadIdx.x] += red[threadIdx.x + s];
        __syncthreads();
    }
    if (threadIdx.x == 0) atomicAdd(lossAcc, red[0]);
}

// ---------------------------------------------------------------------------
// Kernel D: perplexity from histogram + loss finalize.
// loss = m + 0.25*m with m = S/2^20 (exact power-of-two divides).
// ---------------------------------------------------------------------------
__global__ __launch_bounds__(256) void finalize_kernel(
    const int* __restrict__ hist, const float* __restrict__ lossAcc,
    float* __restrict__ out) {
    __shared__ float red[256];
    float acc = 0.0f;
    for (int i = threadIdx.x; i < NE; i += 256) {
        float e = (float)hist[i] * (1.0f / 16384.0f);  // exact /n_tokens
        acc += e * logf(e + 1e-10f);
    }
    red[threadIdx.x] = acc;
    __syncthreads();
    for (int s = 128; s > 0; s >>= 1) {
        if (threadIdx.x < s) red[threadIdx.x] += red[threadIdx.x + s];
        __syncthreads();
    }
    if (threadIdx.x == 0) {
        out[PERP_OFF] = expf(-red[0]);
        float m = lossAcc[0] * (1.0f / 1048576.0f);    // exact /B*T*E
        out[0] = m + 0.25f * m;
    }
}

extern "C" void kernel_launch(void* const* d_in, const int* in_sizes, int n_in,
                              void* d_out, int out_size, void* d_ws, size_t ws_size,
                              hipStream_t stream) {
    const float* z  = (const float*)d_in[0];
    const float* cb = (const float*)d_in[1];
    float* out = (float*)d_out;

    char* ws = (char*)d_ws;
    u64*   part    = (u64*)ws;                                  // 2 MB
    float* nz      = (float*)(ws + (size_t)NSLICE * N_TOK * 8); // 64 KB
    float* ne      = nz + N_TOK;                                // 16 KB
    int*   hist    = (int*)(ne + NE);                           // 16 KB
    float* lossAcc = (float*)(hist + NE);                       // 4 B

    hipLaunchKernelGGL(norms_zero_kernel, dim3(80), dim3(256), 0, stream,
                       z, cb, nz, ne, hist, lossAcc);
    hipLaunchKernelGGL(dist_argmin_kernel, dim3(64, NSLICE), dim3(256), 0, stream,
                       z, cb, nz, ne, part);
    hipLaunchKernelGGL(reduce_gather_kernel, dim3(64), dim3(256), 0, stream,
                       z, cb, part, hist, lossAcc, out);
    hipLaunchKernelGGL(finalize_kernel, dim3(1), dim3(256), 0, stream,
                       hist, lossAcc, out);
}

// Round 3
// 199.327 us; speedup vs baseline: 3.7041x; 1.0866x over previous
//
#include <hip/hip_runtime.h>
#include <math.h>

#define N_TOK   16384
#define EDIM    64
#define NE      4096
#define NSLICE  16
#define CSLICE  (NE / NSLICE)            /* 256 codes per slice   */
#define CHUNK   128                      /* codes per LDS chunk   */
#define TPB     256
#define TOKPT   2                        /* tokens per thread     */
#define ZQ_OFF  1
#define IDX_OFF (1 + N_TOK * EDIM)       /* 1048577 */
#define PERP_OFF (IDX_OFF + N_TOK)       /* 1064961 */

typedef unsigned long long u64;

// ---------------------------------------------------------------------------
// Kernel A: per-row squared norms replicating numpy pairwise_sum (n=64 path:
// 8 accumulators stride 8, then ((r0+r1)+(r2+r3))+((r4+r5)+(r6+r7))),
// with products ROUNDED before summation (contract off). Also zero-inits
// the histogram and loss accumulator in ws.
// ---------------------------------------------------------------------------
__global__ __launch_bounds__(256) void norms_zero_kernel(
    const float* __restrict__ z, const float* __restrict__ cb,
    float* __restrict__ nz, float* __restrict__ ne,
    int* __restrict__ hist, float* __restrict__ lossAcc) {
#pragma clang fp contract(off)
    int i = blockIdx.x * 256 + threadIdx.x;
    if (i < NE) hist[i] = 0;
    if (i == 0) lossAcc[0] = 0.0f;
    const float* row;
    float* dst;
    if (i < N_TOK)            { row = z  + (size_t)i * EDIM;           dst = nz + i; }
    else if (i < N_TOK + NE)  { row = cb + (size_t)(i - N_TOK) * EDIM; dst = ne + (i - N_TOK); }
    else return;

    float r[8];
#pragma unroll
    for (int j = 0; j < 8; ++j) { float v = row[j]; r[j] = v * v; }
#pragma unroll
    for (int b = 8; b < 64; b += 8) {
#pragma unroll
        for (int j = 0; j < 8; ++j) { float v = row[b + j]; r[j] = r[j] + v * v; }
    }
    dst[0] = ((r[0] + r[1]) + (r[2] + r[3])) + ((r[4] + r[5]) + (r[6] + r[7]));
}

// ---------------------------------------------------------------------------
// Kernel B: distances + per-slice argmin, token-blocked.
// One thread = TWO tokens (z for both resident in 128 VGPRs). Codebook chunk
// (128 codes, 32 KB) staged in LDS, read as wave-uniform broadcast float4s;
// each staged float4 feeds 8 FMAs (2 codes x 2 tokens) -> LDS pipe no longer
// co-bottleneck (was 16 b128/code; now 8). 4 independent FMA chains per
// thread keep VALU fed at 2 blocks/CU.
// The per-(token,code) dot is the SAME sequential j-ascending FMA chain as
// the passing round-1/2 kernels (bitwise-identical d -> ties exact).
// d = fma(-2, dot, nz+ne[k]); argmin packed (d_bits<<32)|k, u64 min
// == first-index tie-break (d>0 so float bits monotone).
// ---------------------------------------------------------------------------
__global__ __launch_bounds__(256, 2) void dist_argmin_kernel(
    const float* __restrict__ z, const float* __restrict__ cb,
    const float* __restrict__ nz, const float* __restrict__ ne,
    u64* __restrict__ part) {
    __shared__ float se[CHUNK * EDIM];   // 32 KB
    __shared__ float sne[CHUNK];
    const int tid    = threadIdx.x;
    const int token0 = blockIdx.x * (TPB * TOKPT) + tid;   // tokens tid, tid+256
    const int token1 = token0 + TPB;
    const int slice  = blockIdx.y;

    float zr0[EDIM], zr1[EDIM];
    {
        const float4* zp0 = (const float4*)(z + (size_t)token0 * EDIM);
        const float4* zp1 = (const float4*)(z + (size_t)token1 * EDIM);
#pragma unroll
        for (int j = 0; j < 16; ++j) {
            float4 v = zp0[j];
            zr0[4 * j + 0] = v.x; zr0[4 * j + 1] = v.y;
            zr0[4 * j + 2] = v.z; zr0[4 * j + 3] = v.w;
            float4 w = zp1[j];
            zr1[4 * j + 0] = w.x; zr1[4 * j + 1] = w.y;
            zr1[4 * j + 2] = w.z; zr1[4 * j + 3] = w.w;
        }
    }
    const float tnz0 = nz[token0];
    const float tnz1 = nz[token1];
    u64 best0 = ~0ull, best1 = ~0ull;

#pragma unroll 1
    for (int c = 0; c < CSLICE / CHUNK; ++c) {
        const int kbase = slice * CSLICE + c * CHUNK;
        {
            const float4* src = (const float4*)(cb + (size_t)kbase * EDIM);
            float4* dst = (float4*)se;
#pragma unroll
            for (int r = 0; r < (CHUNK * EDIM / 4) / TPB; ++r)
                dst[r * TPB + tid] = src[r * TPB + tid];
            if (tid < CHUNK / 4)
                ((float4*)sne)[tid] = ((const float4*)(ne + kbase))[tid];
        }
        __syncthreads();

#pragma unroll 1
        for (int k = 0; k < CHUNK; k += 2) {
            const float4* e0 = (const float4*)(se + (size_t)(k + 0) * EDIM);
            const float4* e1 = (const float4*)(se + (size_t)(k + 1) * EDIM);
            float d00 = 0.f, d01 = 0.f, d10 = 0.f, d11 = 0.f;
#pragma unroll
            for (int q = 0; q < 16; ++q) {
                float4 a = e0[q];
                float4 b = e1[q];
                d00 = __builtin_fmaf(zr0[4 * q + 0], a.x, d00);
                d00 = __builtin_fmaf(zr0[4 * q + 1], a.y, d00);
                d00 = __builtin_fmaf(zr0[4 * q + 2], a.z, d00);
                d00 = __builtin_fmaf(zr0[4 * q + 3], a.w, d00);
                d01 = __builtin_fmaf(zr0[4 * q + 0], b.x, d01);
                d01 = __builtin_fmaf(zr0[4 * q + 1], b.y, d01);
                d01 = __builtin_fmaf(zr0[4 * q + 2], b.z, d01);
                d01 = __builtin_fmaf(zr0[4 * q + 3], b.w, d01);
                d10 = __builtin_fmaf(zr1[4 * q + 0], a.x, d10);
                d10 = __builtin_fmaf(zr1[4 * q + 1], a.y, d10);
                d10 = __builtin_fmaf(zr1[4 * q + 2], a.z, d10);
                d10 = __builtin_fmaf(zr1[4 * q + 3], a.w, d10);
                d11 = __builtin_fmaf(zr1[4 * q + 0], b.x, d11);
                d11 = __builtin_fmaf(zr1[4 * q + 1], b.y, d11);
                d11 = __builtin_fmaf(zr1[4 * q + 2], b.z, d11);
                d11 = __builtin_fmaf(zr1[4 * q + 3], b.w, d11);
            }
            const float s0 = sne[k + 0], s1 = sne[k + 1];
            float t00 = __builtin_fmaf(-2.0f, d00, tnz0 + s0);
            float t01 = __builtin_fmaf(-2.0f, d01, tnz0 + s1);
            float t10 = __builtin_fmaf(-2.0f, d10, tnz1 + s0);
            float t11 = __builtin_fmaf(-2.0f, d11, tnz1 + s1);
            u64 p;
            p = ((u64)__float_as_uint(t00) << 32) | (u64)(kbase + k + 0); if (p < best0) best0 = p;
            p = ((u64)__float_as_uint(t01) << 32) | (u64)(kbase + k + 1); if (p < best0) best0 = p;
            p = ((u64)__float_as_uint(t10) << 32) | (u64)(kbase + k + 0); if (p < best1) best1 = p;
            p = ((u64)__float_as_uint(t11) << 32) | (u64)(kbase + k + 1); if (p < best1) best1 = p;
        }
        __syncthreads();
    }
    part[(size_t)slice * N_TOK + token0] = best0;
    part[(size_t)slice * N_TOK + token1] = best1;
}

// ---------------------------------------------------------------------------
// Kernel C: combine 16 slice-partials (u64 min keeps first-index tie-break),
// write idx as float, histogram, gather z_q, write z_q_st = z + (z_q - z)
// exactly as the reference computes it, and accumulate sum((z_q - z)^2).
// ---------------------------------------------------------------------------
__global__ __launch_bounds__(256) void reduce_gather_kernel(
    const float* __restrict__ z, const float* __restrict__ cb,
    const u64* __restrict__ part, int* __restrict__ hist,
    float* __restrict__ lossAcc, float* __restrict__ out) {
    const int t = blockIdx.x * 256 + threadIdx.x;
    u64 best = part[t];
#pragma unroll
    for (int s = 1; s < NSLICE; ++s) {
        u64 p = part[(size_t)s * N_TOK + t];
        if (p < best) best = p;
    }
    const int idx = (int)(best & 0xFFFFFFFFull);
    out[IDX_OFF + t] = (float)idx;
    atomicAdd(&hist[idx], 1);

    const float4* ev = (const float4*)(cb + (size_t)idx * EDIM);
    const float4* zv = (const float4*)(z + (size_t)t * EDIM);
    float* o = out + ZQ_OFF + (size_t)t * EDIM;  // out+1: only 4B-aligned -> scalar stores
    float acc = 0.0f;
#pragma unroll
    for (int j = 0; j < 16; ++j) {
        float4 e = ev[j], zz = zv[j];
        float d;
        d = e.x - zz.x; o[4 * j + 0] = zz.x + d; acc = __builtin_fmaf(d, d, acc);
        d = e.y - zz.y; o[4 * j + 1] = zz.y + d; acc = __builtin_fmaf(d, d, acc);
        d = e.z - zz.z; o[4 * j + 2] = zz.z + d; acc = __builtin_fmaf(d, d, acc);
        d = e.w - zz.w; o[4 * j + 3] = zz.w + d; acc = __builtin_fmaf(d, d, acc);
    }
    __shared__ float red[256];
    red[threadIdx.x] = acc;
    __syncthreads();
    for (int s = 128; s > 0; s >>= 1) {
        if (threadIdx.x < s) red[threadIdx.x] += red[threadIdx.x + s];
        __syncthreads();
    }
    if (threadIdx.x == 0) atomicAdd(lossAcc, red[0]);
}

// ---------------------------------------------------------------------------
// Kernel D: perplexity from histogram + loss finalize.
// loss = m + 0.25*m with m = S/2^20 (exact power-of-two divides).
// ---------------------------------------------------------------------------
__global__ __launch_bounds__(256) void finalize_kernel(
    const int* __restrict__ hist, const float* __restrict__ lossAcc,
    float* __restrict__ out) {
    __shared__ float red[256];
    float acc = 0.0f;
    for (int i = threadIdx.x; i < NE; i += 256) {
        float e = (float)hist[i] * (1.0f / 16384.0f);  // exact /n_tokens
        acc += e * logf(e + 1e-10f);
    }
    red[threadIdx.x] = acc;
    __syncthreads();
    for (int s = 128; s > 0; s >>= 1) {
        if (threadIdx.x < s) red[threadIdx.x] += red[threadIdx.x + s];
        __syncthreads();
    }
    if (threadIdx.x == 0) {
        out[PERP_OFF] = expf(-red[0]);
        float m = lossAcc[0] * (1.0f / 1048576.0f);    // exact /B*T*E
        out[0] = m + 0.25f * m;
    }
}

extern "C" void kernel_launch(void* const* d_in, const int* in_sizes, int n_in,
                              void* d_out, int out_size, void* d_ws, size_t ws_size,
                              hipStream_t stream) {
    const float* z  = (const float*)d_in[0];
    const float* cb = (const float*)d_in[1];
    float* out = (float*)d_out;

    char* ws = (char*)d_ws;
    u64*   part    = (u64*)ws;                                  // 2 MB
    float* nz      = (float*)(ws + (size_t)NSLICE * N_TOK * 8); // 64 KB
    float* ne      = nz + N_TOK;                                // 16 KB
    int*   hist    = (int*)(ne + NE);                           // 16 KB
    float* lossAcc = (float*)(hist + NE);                       // 4 B

    hipLaunchKernelGGL(norms_zero_kernel, dim3(80), dim3(256), 0, stream,
                       z, cb, nz, ne, hist, lossAcc);
    hipLaunchKernelGGL(dist_argmin_kernel,
                       dim3(N_TOK / (TPB * TOKPT), NSLICE), dim3(TPB), 0, stream,
                       z, cb, nz, ne, part);
    hipLaunchKernelGGL(reduce_gather_kernel, dim3(64), dim3(256), 0, stream,
                       z, cb, part, hist, lossAcc, out);
    hipLaunchKernelGGL(finalize_kernel, dim3(1), dim3(256), 0, stream,
                       hist, lossAcc, out);
}